// Round 1
// baseline (612.895 us; speedup 1.0000x reference)
//
#include <hip/hip_runtime.h>
#include <cstdint>
#include <cstddef>

#define HD 128            // hidden
#define KD 256            // 2*hidden (concat src,dst)
#define TILE_E 32         // edges per block
#define KC 32             // k-chunk staged per buffer
#define NCHUNK (KD / KC)  // 8
#define BLOCK 256

typedef const __attribute__((address_space(1))) void gvoid_t;
typedef __attribute__((address_space(3))) void lvoid_t;

__device__ __forceinline__ void gload_lds16(const void* g, void* l) {
    // async global->LDS, 16B per lane; LDS dest = wave-uniform base + lane*16
    __builtin_amdgcn_global_load_lds((gvoid_t*)g, (lvoid_t*)l, 16, 0, 0);
}

__global__ __launch_bounds__(BLOCK, 2) void edge_decoder_kernel(
    const float* __restrict__ z, const int* __restrict__ eli, const int E,
    const float* __restrict__ w1, const float* __restrict__ b1,
    const float* __restrict__ w2, const float* __restrict__ b2,
    float* __restrict__ out)
{
    __shared__ float sZ[TILE_E][KD];   // 32 KB: row e = [src(128) | dst(128)]
    __shared__ float sW[2][KC][HD];    // 2 x 16 KB double-buffered w1 chunks

    const int t    = threadIdx.x;
    const int wave = t >> 6;
    const int lane = t & 63;
    const int e0   = blockIdx.x * TILE_E;

    // ---- stage Z tile: one 1KB global_load_lds per edge (8 per wave).
    // lanes 0..31 fetch src row, lanes 32..63 fetch dst row; LDS base uniform.
    #pragma unroll
    for (int q = 0; q < TILE_E / 4; ++q) {
        const int e = wave * (TILE_E / 4) + q;
        int ge = e0 + e;
        if (ge >= E) ge = E - 1;  // uniform clamp (E % 32 == 0 normally)
        const int node = (lane < 32) ? eli[ge] : eli[E + ge];
        const float* gp = z + (size_t)node * HD + (size_t)(lane & 31) * 4;
        gload_lds16(gp, &sZ[e][0]);
    }
    // ---- stage W chunk 0 (16 KB = 16 x 1KB instructions, 4 per wave)
    {
        float* swb = &sW[0][0][0];
        #pragma unroll
        for (int q = 0; q < 4; ++q) {
            const int inst = wave * 4 + q;
            gload_lds16(w1 + inst * 256 + lane * 4, swb + inst * 256);
        }
    }
    __syncthreads();

    const int cg = t & 31;   // col group: cols cg*4 .. cg*4+3
    const int eg = t >> 5;   // edge group: edges eg*4 .. eg*4+3
    const int c0 = cg * 4;

    float acc[4][4] = {{0.f, 0.f, 0.f, 0.f}};

    for (int kc = 0; kc < NCHUNK; ++kc) {
        const int buf = kc & 1;
        if (kc + 1 < NCHUNK) {  // prefetch next w1 chunk into other buffer
            const float* gw = w1 + (size_t)(kc + 1) * KC * HD;
            float* swb = &sW[buf ^ 1][0][0];
            #pragma unroll
            for (int q = 0; q < 4; ++q) {
                const int inst = wave * 4 + q;
                gload_lds16(gw + inst * 256 + lane * 4, swb + inst * 256);
            }
        }
        #pragma unroll
        for (int k4 = 0; k4 < KC / 4; ++k4) {
            float zr[4][4];
            #pragma unroll
            for (int i = 0; i < 4; ++i)
                *(float4*)(&zr[i][0]) =
                    *(const float4*)(&sZ[eg * 4 + i][kc * KC + k4 * 4]);
            #pragma unroll
            for (int kk = 0; kk < 4; ++kk) {
                const float4 wv = *(const float4*)(&sW[buf][k4 * 4 + kk][c0]);
                #pragma unroll
                for (int i = 0; i < 4; ++i) {
                    acc[i][0] = fmaf(zr[i][kk], wv.x, acc[i][0]);
                    acc[i][1] = fmaf(zr[i][kk], wv.y, acc[i][1]);
                    acc[i][2] = fmaf(zr[i][kk], wv.z, acc[i][2]);
                    acc[i][3] = fmaf(zr[i][kk], wv.w, acc[i][3]);
                }
            }
        }
        __syncthreads();
    }

    // ---- epilogue: bias + relu + layer2 dot, reduce over 32 col-lanes
    const float4 b1v = *(const float4*)(&b1[c0]);
    const float4 w2v = *(const float4*)(&w2[c0]);
    const float bb2  = b2[0];

    float part[4];
    #pragma unroll
    for (int i = 0; i < 4; ++i) {
        const float hx = fmaxf(acc[i][0] + b1v.x, 0.f);
        const float hy = fmaxf(acc[i][1] + b1v.y, 0.f);
        const float hz = fmaxf(acc[i][2] + b1v.z, 0.f);
        const float hw = fmaxf(acc[i][3] + b1v.w, 0.f);
        part[i] = hx * w2v.x + hy * w2v.y + hz * w2v.z + hw * w2v.w;
    }
    #pragma unroll
    for (int m = 16; m >= 1; m >>= 1) {
        #pragma unroll
        for (int i = 0; i < 4; ++i)
            part[i] += __shfl_xor(part[i], m, 32);
    }
    if (cg == 0) {
        #pragma unroll
        for (int i = 0; i < 4; ++i) {
            const int ge = e0 + eg * 4 + i;
            if (ge < E) {
                const float v = part[i] + bb2;
                out[ge] = 1.0f / (1.0f + __expf(-v));
            }
        }
    }
}

extern "C" void kernel_launch(void* const* d_in, const int* in_sizes, int n_in,
                              void* d_out, int out_size, void* d_ws, size_t ws_size,
                              hipStream_t stream) {
    const float* z  = (const float*)d_in[0];
    const int*   eli = (const int*)d_in[1];   // harness delivers integer inputs as int32
    const float* w1 = (const float*)d_in[2];
    const float* b1 = (const float*)d_in[3];
    const float* w2 = (const float*)d_in[4];
    const float* b2 = (const float*)d_in[5];
    float* out = (float*)d_out;

    const int E = in_sizes[1] / 2;            // 640000
    const int nblocks = (E + TILE_E - 1) / TILE_E;
    edge_decoder_kernel<<<nblocks, BLOCK, 0, stream>>>(z, eli, E, w1, b1, w2, b2, out);
}

// Round 2
// 118.725 us; speedup vs baseline: 5.1623x; 5.1623x over previous
//
#include <hip/hip_runtime.h>
#include <cstdint>
#include <cstddef>

#define HD 128
#define KD 256
#define TE 128        // edges per block (main kernel)
#define BLOCK 256

typedef __attribute__((ext_vector_type(8))) short bf16x8;
typedef __attribute__((ext_vector_type(4))) float f32x4;

typedef const __attribute__((address_space(1))) void gv_t;
typedef __attribute__((address_space(3))) void lv_t;

__device__ __forceinline__ void gload16(const void* g, void* l) {
    // async global->LDS: per-lane GLOBAL addr, wave-uniform LDS base + lane*16
    __builtin_amdgcn_global_load_lds((gv_t*)g, (lv_t*)l, 16, 0, 0);
}

__device__ __forceinline__ unsigned short f2bf(float x) {   // RNE f32->bf16
    unsigned u = __float_as_uint(x);
    u = (u + 0x7fffu + ((u >> 16) & 1u)) >> 16;
    return (unsigned short)u;
}

// ---------------- pre-pass: z_state f32 -> bf16 mirror ----------------
__global__ void convert_z_kernel(const float* __restrict__ z,
                                 unsigned short* __restrict__ zb, int n4) {
    int i = blockIdx.x * blockDim.x + threadIdx.x;
    if (i < n4) {
        float4 v = ((const float4*)z)[i];
        ushort4 o;
        o.x = f2bf(v.x); o.y = f2bf(v.y); o.z = f2bf(v.z); o.w = f2bf(v.w);
        ((ushort4*)zb)[i] = o;
    }
}

// ---------------- pre-pass: w1 f32 -> bf16 MFMA B-fragment order -------
// layout: elem idx = ((kt*8 + nf)*64 + lane)*8 + j  holds  w1[kt*32+(lane>>4)*8+j][nf*16+(lane&15)]
__global__ void pack_w1_kernel(const float* __restrict__ w1,
                               unsigned short* __restrict__ w1p) {
    int tid = blockIdx.x * blockDim.x + threadIdx.x;  // 0..4095
    int lane = tid & 63, nf = (tid >> 6) & 7, kt = tid >> 9;
    int col = nf * 16 + (lane & 15);
    int k0 = kt * 32 + (lane >> 4) * 8;
    #pragma unroll
    for (int j = 0; j < 8; ++j)
        w1p[(size_t)tid * 8 + j] = f2bf(w1[(size_t)(k0 + j) * HD + col]);
}

// ---------------- main: gather + bf16 MFMA MLP -------------------------
__global__ __launch_bounds__(BLOCK, 2) void edge_mfma_kernel(
    const unsigned short* __restrict__ zb,   // [N][128] bf16
    const unsigned short* __restrict__ w1p,  // packed frags
    const int* __restrict__ eli, const int E,
    const float* __restrict__ b1, const float* __restrict__ w2,
    const float* __restrict__ b2, float* __restrict__ out)
{
    // sZ: logical [TE][256] bf16 (512 B/row), physical byte = logical ^ ((row&7)<<4)
    __shared__ __attribute__((aligned(16))) unsigned short sZ[TE * KD];   // 64 KB
    __shared__ __attribute__((aligned(16))) unsigned short sW[2][8 * 64 * 8]; // 16 KB

    const int t = threadIdx.x;
    const int wave = t >> 6;
    const int l = t & 63;
    const int e0 = blockIdx.x * TE;

    // stage Z: one 1KB inst covers 2 swizzled rows; source addr pre-swizzled
    #pragma unroll
    for (int q = 0; q < 16; ++q) {
        const int epair = wave * 32 + q * 2;
        const int r = epair + (l >> 5);
        int ge = e0 + r; if (ge >= E) ge = E - 1;
        const int ob = ((l & 31) * 16) ^ ((r & 7) << 4);   // byte within logical row
        const int node = (ob < 256) ? eli[ge] : eli[E + ge];
        const char* gp = (const char*)zb + (size_t)node * 256 + (ob & 255);
        gload16(gp, (char*)sZ + epair * 512);
    }
    // stage W k-tile 0 (8 KB)
    #pragma unroll
    for (int q = 0; q < 2; ++q) {
        const int i = wave * 2 + q;
        gload16((const char*)w1p + i * 1024 + l * 16, (char*)sW[0] + i * 1024);
    }
    __syncthreads();

    const int waveM = wave >> 1;   // 2 waves along edges (64 each)
    const int waveN = wave & 1;    // 2 waves along cols  (64 each)

    f32x4 acc[4][4];
    #pragma unroll
    for (int i = 0; i < 4; ++i)
        #pragma unroll
        for (int j = 0; j < 4; ++j) acc[i][j] = (f32x4)(0.f);

    for (int kt = 0; kt < 8; ++kt) {
        const int buf = kt & 1;
        if (kt < 7) {  // prefetch next w1 k-slice
            #pragma unroll
            for (int q = 0; q < 2; ++q) {
                const int i = wave * 2 + q;
                gload16((const char*)w1p + (size_t)(kt + 1) * 8192 + i * 1024 + l * 16,
                        (char*)sW[buf ^ 1] + i * 1024);
            }
        }
        bf16x8 af[4], bfr[4];
        #pragma unroll
        for (int mf = 0; mf < 4; ++mf) {
            const int r = waveM * 64 + mf * 16 + (l & 15);
            const int o = r * 512 + kt * 64 + ((l >> 4) * 16);
            af[mf] = *(const bf16x8*)((const char*)sZ + (o ^ ((r & 7) << 4)));
        }
        #pragma unroll
        for (int nf = 0; nf < 4; ++nf)
            bfr[nf] = *(const bf16x8*)((const char*)sW[buf] + (waveN * 4 + nf) * 1024 + l * 16);
        #pragma unroll
        for (int mf = 0; mf < 4; ++mf)
            #pragma unroll
            for (int nf = 0; nf < 4; ++nf)
                acc[mf][nf] = __builtin_amdgcn_mfma_f32_16x16x32_bf16(
                    af[mf], bfr[nf], acc[mf][nf], 0, 0, 0);
        __syncthreads();
    }

    // epilogue: bias+relu+w2 dot in fp32; D layout: col=l&15, row=(l>>4)*4+j
    float b1v[4], w2v[4];
    #pragma unroll
    for (int nf = 0; nf < 4; ++nf) {
        const int c = waveN * 64 + nf * 16 + (l & 15);
        b1v[nf] = b1[c];
        w2v[nf] = w2[c];
    }
    float part[4][4];
    #pragma unroll
    for (int mf = 0; mf < 4; ++mf)
        #pragma unroll
        for (int j = 0; j < 4; ++j) {
            float p = 0.f;
            #pragma unroll
            for (int nf = 0; nf < 4; ++nf)
                p += fmaxf(acc[mf][nf][j] + b1v[nf], 0.f) * w2v[nf];
            #pragma unroll
            for (int m = 1; m <= 8; m <<= 1) p += __shfl_xor(p, m);
            part[mf][j] = p;   // valid in all 16 lanes of each group
        }

    float* sRed = (float*)sW;  // sW dead after k-loop (last iter ends in barrier)
    if (waveN == 1 && (l & 15) == 0) {
        #pragma unroll
        for (int mf = 0; mf < 4; ++mf)
            #pragma unroll
            for (int j = 0; j < 4; ++j)
                sRed[waveM * 64 + mf * 16 + (l >> 4) * 4 + j] = part[mf][j];
    }
    __syncthreads();
    if (waveN == 0 && (l & 15) == 0) {
        const float bb2 = b2[0];
        #pragma unroll
        for (int mf = 0; mf < 4; ++mf)
            #pragma unroll
            for (int j = 0; j < 4; ++j) {
                const int row = waveM * 64 + mf * 16 + (l >> 4) * 4 + j;
                const int ge = e0 + row;
                if (ge < E) {
                    const float v = part[mf][j] + sRed[row] + bb2;
                    out[ge] = 1.f / (1.f + __expf(-v));
                }
            }
    }
}

// ---------------- fallback (round-1 fp32 kernel, used if ws too small) ----
__global__ __launch_bounds__(256, 2) void edge_decoder_fp32_kernel(
    const float* __restrict__ z, const int* __restrict__ eli, const int E,
    const float* __restrict__ w1, const float* __restrict__ b1,
    const float* __restrict__ w2, const float* __restrict__ b2,
    float* __restrict__ out)
{
    __shared__ float sZ[32][256];
    __shared__ float sW[2][32][128];
    const int t = threadIdx.x, wave = t >> 6, lane = t & 63;
    const int e0 = blockIdx.x * 32;
    #pragma unroll
    for (int q = 0; q < 8; ++q) {
        const int e = wave * 8 + q;
        int ge = e0 + e; if (ge >= E) ge = E - 1;
        const int node = (lane < 32) ? eli[ge] : eli[E + ge];
        gload16(z + (size_t)node * HD + (size_t)(lane & 31) * 4, &sZ[e][0]);
    }
    #pragma unroll
    for (int q = 0; q < 4; ++q) {
        const int inst = wave * 4 + q;
        gload16(w1 + inst * 256 + lane * 4, &sW[0][0][0] + inst * 256);
    }
    __syncthreads();
    const int cg = t & 31, eg = t >> 5, c0 = cg * 4;
    float acc[4][4] = {{0.f,0.f,0.f,0.f}};
    for (int kc = 0; kc < 8; ++kc) {
        const int buf = kc & 1;
        if (kc + 1 < 8) {
            const float* gw = w1 + (size_t)(kc + 1) * 32 * HD;
            #pragma unroll
            for (int q = 0; q < 4; ++q) {
                const int inst = wave * 4 + q;
                gload16(gw + inst * 256 + lane * 4, &sW[buf ^ 1][0][0] + inst * 256);
            }
        }
        #pragma unroll
        for (int k4 = 0; k4 < 8; ++k4) {
            float zr[4][4];
            #pragma unroll
            for (int i = 0; i < 4; ++i)
                *(float4*)(&zr[i][0]) = *(const float4*)(&sZ[eg*4+i][kc*32 + k4*4]);
            #pragma unroll
            for (int kk = 0; kk < 4; ++kk) {
                const float4 wv = *(const float4*)(&sW[buf][k4*4+kk][c0]);
                #pragma unroll
                for (int i = 0; i < 4; ++i) {
                    acc[i][0] = fmaf(zr[i][kk], wv.x, acc[i][0]);
                    acc[i][1] = fmaf(zr[i][kk], wv.y, acc[i][1]);
                    acc[i][2] = fmaf(zr[i][kk], wv.z, acc[i][2]);
                    acc[i][3] = fmaf(zr[i][kk], wv.w, acc[i][3]);
                }
            }
        }
        __syncthreads();
    }
    const float4 b1v = *(const float4*)(&b1[c0]);
    const float4 w2v = *(const float4*)(&w2[c0]);
    const float bb2 = b2[0];
    float part[4];
    #pragma unroll
    for (int i = 0; i < 4; ++i) {
        part[i] = fmaxf(acc[i][0]+b1v.x,0.f)*w2v.x + fmaxf(acc[i][1]+b1v.y,0.f)*w2v.y
                + fmaxf(acc[i][2]+b1v.z,0.f)*w2v.z + fmaxf(acc[i][3]+b1v.w,0.f)*w2v.w;
    }
    #pragma unroll
    for (int m = 16; m >= 1; m >>= 1)
        #pragma unroll
        for (int i = 0; i < 4; ++i) part[i] += __shfl_xor(part[i], m, 32);
    if (cg == 0) {
        #pragma unroll
        for (int i = 0; i < 4; ++i) {
            const int ge = e0 + eg * 4 + i;
            if (ge < E) out[ge] = 1.0f / (1.0f + __expf(-(part[i] + bb2)));
        }
    }
}

extern "C" void kernel_launch(void* const* d_in, const int* in_sizes, int n_in,
                              void* d_out, int out_size, void* d_ws, size_t ws_size,
                              hipStream_t stream) {
    const float* z  = (const float*)d_in[0];
    const int* eli  = (const int*)d_in[1];
    const float* w1 = (const float*)d_in[2];
    const float* b1 = (const float*)d_in[3];
    const float* w2 = (const float*)d_in[4];
    const float* b2 = (const float*)d_in[5];
    float* out = (float*)d_out;

    const int E  = in_sizes[1] / 2;       // 640000
    const int NN = in_sizes[0] / HD;      // 100000

    const size_t need = 65536 + (size_t)NN * HD * 2;  // w1p + zb
    if (ws_size >= need) {
        unsigned short* w1p = (unsigned short*)d_ws;
        unsigned short* zb  = (unsigned short*)((char*)d_ws + 65536);
        const int n4 = NN * HD / 4;
        convert_z_kernel<<<(n4 + 255) / 256, 256, 0, stream>>>(z, zb, n4);
        pack_w1_kernel<<<16, 256, 0, stream>>>(w1, w1p);
        edge_mfma_kernel<<<(E + TE - 1) / TE, BLOCK, 0, stream>>>(
            zb, w1p, eli, E, b1, w2, b2, out);
    } else {
        edge_decoder_fp32_kernel<<<(E + 31) / 32, 256, 0, stream>>>(
            z, eli, E, w1, b1, w2, b2, out);
    }
}